// Round 13
// baseline (962.026 us; speedup 1.0000x reference)
//
#include <hip/hip_runtime.h>

// Problem constants: B=64, T=256, V=4096, H=512
// Inputs: x[B*T] i32, Wxh[V,H] f32, Whh[H,H] f32, bh[H] f32, Wo[H,V] f32, Bo[V] f32
// Output: out[B,T,V] f32 = (scan hs) @ Wo + Bo

typedef __fp16 half2_t __attribute__((ext_vector_type(2)));
typedef __attribute__((ext_vector_type(8))) short short8;   // 8 bf16 (MFMA A/B frag)
typedef __attribute__((ext_vector_type(4))) float f32x4;    // MFMA C/D frag
typedef unsigned int u32x4 __attribute__((ext_vector_type(4)));  // asm-friendly 16B

__device__ __forceinline__ unsigned short f32_to_bf16(float f) {
  unsigned int u = __builtin_bit_cast(unsigned int, f);
  u = (u + 0x7FFFu + ((u >> 16) & 1u)) >> 16;  // RNE
  return (unsigned short)u;
}

__device__ __forceinline__ unsigned int pack_f16x2(float a, float b) {
  half2_t h = __builtin_amdgcn_cvt_pkrtz(a, b);
  return __builtin_bit_cast(unsigned int, h);
}

__device__ __forceinline__ float fdot2_(unsigned int w, unsigned int h, float acc) {
  return __builtin_amdgcn_fdot2(__builtin_bit_cast(half2_t, w),
                                __builtin_bit_cast(half2_t, h), acc, false);
}

__device__ __forceinline__ void glds16(const void* g, void* lds) {
  __builtin_amdgcn_global_load_lds(
      (const __attribute__((address_space(1))) unsigned int*)g,
      (__attribute__((address_space(3))) unsigned int*)lds, 16, 0, 0);
}

// ---------------------------------------------------------------------------
// Prep 1a: Whh -> WhhP7 (f16 pairs; chunks c=0..3 feed the LDS quarter).
// u32 idx = U*4+e, U = ((i*16+c)*4+o)*128+g holds pair p = i*64+c*4+e
// (h elems 2p,2p+1) of column j = o*128+g.
// ---------------------------------------------------------------------------
__global__ __launch_bounds__(256) void pack_whh7(const float* __restrict__ Whh,
                                                 unsigned int* __restrict__ WhhP7) {
  int idx = blockIdx.x * 256 + threadIdx.x;  // 131072 u32 total
  int e = idx & 3;
  int U = idx >> 2;
  int g = U & 127;
  int o = (U >> 7) & 3;
  int c = (U >> 9) & 15;
  int i = U >> 13;
  int p = i * 64 + c * 4 + e;
  int j = o * 128 + g;
  float f0 = Whh[(2 * p) * 512 + j];
  float f1 = Whh[(2 * p + 1) * 512 + j];
  WhhP7[idx] = pack_f16x2(f0, f1);
}

// ---------------------------------------------------------------------------
// Prep 1b: stream layout for the asm pipeline. uint4 index
// Q = s*1024 + (i*128+g)*2 + u, slot s = d*4+o (d=0..5 batch, o=colgrp),
// u=0 -> chunk 4+2d, u=1 -> chunk 5+2d of column j=o*128+g, k-quarter i.
// Thread (g,i) slot loads: 2 contiguous uint4 (32B) -> lanes coalesced
// (wave covers 2KB); slot bases are plain C pointers (no big immediates).
// ---------------------------------------------------------------------------
__global__ __launch_bounds__(256) void pack_whhS(const float* __restrict__ Whh,
                                                 unsigned int* __restrict__ WhhS) {
  int idx = blockIdx.x * 256 + threadIdx.x;  // 98304 u32 total
  int e = idx & 3;
  int Q = idx >> 2;
  int u = Q & 1;
  int r = (Q >> 1) & 511;      // i*128+g
  int s = Q >> 10;             // d*4+o
  int o = s & 3;
  int d = s >> 2;
  int i = r >> 7;
  int g = r & 127;
  int c = 4 + 2 * d + u;       // chunk 4..15
  int p = i * 64 + c * 4 + e;  // f16-pair index
  int j = o * 128 + g;         // column
  float f0 = Whh[(2 * p) * 512 + j];
  float f1 = Whh[(2 * p + 1) * 512 + j];
  WhhS[idx] = pack_f16x2(f0, f1);
}

// ---------------------------------------------------------------------------
// Prep 2: Wo [h][v] f32 -> WoT [v][h] bf16
// ---------------------------------------------------------------------------
__global__ __launch_bounds__(256) void transpose_wo(const float* __restrict__ Wo,
                                                    unsigned short* __restrict__ WoT) {
  __shared__ float tile[64][65];
  const int tv = blockIdx.x;   // 0..63  (V/64)
  const int th = blockIdx.y;   // 0..7   (H/64)
  const int tid = threadIdx.x;
  const int c = tid & 63, r4 = tid >> 6;
#pragma unroll
  for (int p = 0; p < 16; ++p) {
    int hl = p * 4 + r4;
    tile[hl][c] = Wo[(size_t)(th * 64 + hl) * 4096 + tv * 64 + c];
  }
  __syncthreads();
#pragma unroll
  for (int p = 0; p < 16; ++p) {
    int vl = p * 4 + r4;
    WoT[(size_t)(tv * 64 + vl) * 512 + th * 64 + c] = f32_to_bf16(tile[c][vl]);
  }
}

// ---------------------------------------------------------------------------
// Recurrence v9: FORCED deep load pipeline (T3/T4 pattern). R4-R12 lesson:
// hipcc narrows any C-level load window to ~2-3 outstanding -> latency-
// serialized (~6 L2 round-trips/step). Fix: issue the 48 streamed uint4 as
// inline-asm global_load_dwordx4 in 6 batches of 8 with counted
// s_waitcnt vmcnt(16/8/0) + sched_barrier(0) (rule #18). 3 batches (24
// uint4/lane = 192 KB/CU) stay in flight BY CONSTRUCTION. LDS quarter
// (chunks 0-3, 128 KB) unchanged; h double-buffered LDS; 2 barriers/step.
// xv is force-materialized before the stream so compiler vmcnt bookkeeping
// never drains the queue mid-pipeline.
// ---------------------------------------------------------------------------
#define DD4(A, W, H) do { A = fdot2_(W.x, H.x, A); A = fdot2_(W.y, H.y, A); \
                          A = fdot2_(W.z, H.z, A); A = fdot2_(W.w, H.w, A); } while (0)

#define WL(c_, o_) wlds[((i * 4 + (c_)) * 4 + (o_)) * 128 + g]

#define DOTL(c_) do { const uint4 hc = hb[i16 + (c_)]; \
  const uint4 w0_ = WL(c_, 0); const uint4 w1_ = WL(c_, 1); \
  const uint4 w2_ = WL(c_, 2); const uint4 w3_ = WL(c_, 3); \
  DD4(a0, w0_, hc); DD4(a1, w1_, hc); DD4(a2, w2_, hc); DD4(a3, w3_, hc); } while (0)

// Issue one batch d_: 8 loads (4 slots x 2 contiguous uint4), outputs pinned.
#define ISSUE(P, d_) \
  asm volatile( \
    "global_load_dwordx4 %0, %8, off\n\t" \
    "global_load_dwordx4 %1, %8, off offset:16\n\t" \
    "global_load_dwordx4 %2, %9, off\n\t" \
    "global_load_dwordx4 %3, %9, off offset:16\n\t" \
    "global_load_dwordx4 %4, %10, off\n\t" \
    "global_load_dwordx4 %5, %10, off offset:16\n\t" \
    "global_load_dwordx4 %6, %11, off\n\t" \
    "global_load_dwordx4 %7, %11, off offset:16" \
    : "=v"(P##_0), "=v"(P##_1), "=v"(P##_2), "=v"(P##_3), \
      "=v"(P##_4), "=v"(P##_5), "=v"(P##_6), "=v"(P##_7) \
    : "v"(WS4 + ((d_) * 4 + 0) * 1024 + r2), "v"(WS4 + ((d_) * 4 + 1) * 1024 + r2), \
      "v"(WS4 + ((d_) * 4 + 2) * 1024 + r2), "v"(WS4 + ((d_) * 4 + 3) * 1024 + r2) \
    : "memory")

#define WAITV(n_) do { asm volatile("s_waitcnt vmcnt(" #n_ ")" ::: "memory"); \
                       __builtin_amdgcn_sched_barrier(0); } while (0)

// Consume batch d_ from buffer P: u=0 pairs with h chunk 4+2d, u=1 with 5+2d.
#define CONSUME(P, d_) do { \
  const uint4 hA = hb[i16 + 4 + 2 * (d_)]; const uint4 hB = hb[i16 + 5 + 2 * (d_)]; \
  DD4(a0, P##_0, hA); DD4(a0, P##_1, hB); \
  DD4(a1, P##_2, hA); DD4(a1, P##_3, hB); \
  DD4(a2, P##_4, hA); DD4(a2, P##_5, hB); \
  DD4(a3, P##_6, hA); DD4(a3, P##_7, hB); } while (0)

__global__ __launch_bounds__(512)
__attribute__((amdgpu_waves_per_eu(2, 2)))
void rnn_scan9(const int* __restrict__ x,
               const float* Wxh,
               const unsigned int* WhhP7,
               const unsigned int* WhhS,
               const float* __restrict__ bh,
               unsigned short* hs) {
  __shared__ uint4 wlds[8192];   // 128 KB: f16 weight chunks c=0..3
  __shared__ uint4 hbuf[128];    // 2 x 512 h f16 (double buffer)
  __shared__ float pbuf[2048];   // partials [i][j]
  __shared__ int toks[256];
  const int b = blockIdx.x;
  const int tid = threadIdx.x;
  const int g = tid & 127;
  const int i = tid >> 7;        // k-quarter (wave-uniform)
  const int i16 = i * 16;
  const int r2 = (i * 128 + g) * 2;
  const uint4* W4 = (const uint4*)WhhP7;
  const u32x4* WS4 = (const u32x4*)WhhS;

  // stage f16 chunks 0-3 into LDS: dst L=((i*4+cc)*4+o)*128+g, src += i*6144
#pragma unroll
  for (int it = 0; it < 16; ++it) {
    int L = it * 512 + tid;
    wlds[L] = W4[(size_t)L + (size_t)(L >> 11) * 6144];
  }
  if (tid < 64) hbuf[tid] = make_uint4(0u, 0u, 0u, 0u);  // h0 = 0 (buf 0)
  if (tid < 256) toks[tid] = x[b * 256 + tid];
  const float bhj = bh[tid];
  __syncthreads();

  unsigned short* hb16 = (unsigned short*)hbuf;  // [2][512] u16 view

  for (int t = 0; t < 256; ++t) {
    const int cur = t & 1;
    const uint4* hb = hbuf + cur * 64;
    const int tok = toks[t];

    const float xv = Wxh[(size_t)tok * 512 + tid];  // L2/L3-hot, coalesced
    asm volatile("" :: "v"(xv));  // materialize xv (its vmcnt wait) BEFORE stream

    u32x4 P0_0, P0_1, P0_2, P0_3, P0_4, P0_5, P0_6, P0_7;
    u32x4 P1_0, P1_1, P1_2, P1_3, P1_4, P1_5, P1_6, P1_7;
    u32x4 P2_0, P2_1, P2_2, P2_3, P2_4, P2_5, P2_6, P2_7;

    ISSUE(P0, 0);
    ISSUE(P1, 1);
    ISSUE(P2, 2);                // 24 loads outstanding

    float a0 = 0.f, a1 = 0.f, a2 = 0.f, a3 = 0.f;
    DOTL(0); DOTL(1); DOTL(2); DOTL(3);   // LDS quarter hides batch-0 latency

    WAITV(16); CONSUME(P0, 0); ISSUE(P0, 3);
    WAITV(16); CONSUME(P1, 1); ISSUE(P1, 4);
    WAITV(16); CONSUME(P2, 2); ISSUE(P2, 5);
    WAITV(16); CONSUME(P0, 3);
    WAITV(8);  CONSUME(P1, 4);
    WAITV(0);  CONSUME(P2, 5);

    pbuf[i * 512 + 0 * 128 + g] = a0;
    pbuf[i * 512 + 1 * 128 + g] = a1;
    pbuf[i * 512 + 2 * 128 + g] = a2;
    pbuf[i * 512 + 3 * 128 + g] = a3;
    __syncthreads();

    // finalize output j = tid
    const float s = pbuf[tid] + pbuf[tid + 512] + pbuf[tid + 1024] + pbuf[tid + 1536];
    const float h = tanhf(xv + s + bhj);
    hs[(size_t)(b * 256 + t) * 512 + tid] = f32_to_bf16(h);
    half2_t hp2 = __builtin_amdgcn_cvt_pkrtz(h, h);
    hb16[(cur ^ 1) * 512 + tid] =
        (unsigned short)(__builtin_bit_cast(unsigned int, hp2) & 0xFFFFu);
    __syncthreads();  // next h complete; pbuf reusable
  }
}

// ---------------------------------------------------------------------------
// Output GEMM: C[16384,4096] = A[16384,512](bf16) @ WoT^T + Bo.  m97 structure.
// ---------------------------------------------------------------------------
__global__ __launch_bounds__(256) void gemm_out(const unsigned short* __restrict__ A,
                                                const unsigned short* __restrict__ Bt,
                                                const float* __restrict__ Bo,
                                                float* __restrict__ C) {
  __shared__ alignas(16) unsigned short As[128 * 32];
  __shared__ alignas(16) unsigned short Bs[128 * 32];
  const int tid = threadIdx.x;
  const int lane = tid & 63, wid = tid >> 6;
  const int bn = blockIdx.x & 31, bm = blockIdx.x >> 5;
  const int wr = wid >> 1, wc = wid & 1;

  f32x4 acc[4][4] = {};

  const unsigned short* Ag = A + (size_t)(bm * 128 + (tid >> 2)) * 512 + (tid & 3) * 8;
  const unsigned short* Bg = Bt + (size_t)(bn * 128 + (tid >> 2)) * 512 + (tid & 3) * 8;
  char* AsW = (char*)As + wid * 1024;
  char* BsW = (char*)Bs + wid * 1024;

  const int laneRow = lane & 15;
  const int k0 = (lane >> 4) * 8;

  for (int kt = 0; kt < 16; ++kt) {
    __syncthreads();
    const unsigned short* a0 = Ag + kt * 32;
    const unsigned short* b0 = Bg + kt * 32;
    glds16(a0,            AsW);
    glds16(a0 + 64 * 512, AsW + 4096);
    glds16(b0,            BsW);
    glds16(b0 + 64 * 512, BsW + 4096);
    __syncthreads();

    short8 af[4], bf[4];
#pragma unroll
    for (int f = 0; f < 4; ++f)
      af[f] = *(const short8*)&As[(wr * 64 + f * 16 + laneRow) * 32 + k0];
#pragma unroll
    for (int f = 0; f < 4; ++f)
      bf[f] = *(const short8*)&Bs[(wc * 64 + f * 16 + laneRow) * 32 + k0];
#pragma unroll
    for (int fm = 0; fm < 4; ++fm)
#pragma unroll
      for (int fn = 0; fn < 4; ++fn)
        acc[fm][fn] = __builtin_amdgcn_mfma_f32_16x16x32_bf16(af[fm], bf[fn], acc[fm][fn], 0, 0, 0);
  }

  const int mg0 = bm * 128 + wr * 64, ng0 = bn * 128 + wc * 64;
#pragma unroll
  for (int fn = 0; fn < 4; ++fn) {
    const int col = ng0 + fn * 16 + laneRow;
    const float bo = Bo[col];
#pragma unroll
    for (int fm = 0; fm < 4; ++fm) {
      const int row0 = mg0 + fm * 16 + (lane >> 4) * 4;
#pragma unroll
      for (int r = 0; r < 4; ++r)
        C[(size_t)(row0 + r) * 4096 + col] = acc[fm][fn][r] + bo;
    }
  }
}

// ---------------------------------------------------------------------------
extern "C" void kernel_launch(void* const* d_in, const int* in_sizes, int n_in,
                              void* d_out, int out_size, void* d_ws, size_t ws_size,
                              hipStream_t stream) {
  (void)in_sizes; (void)n_in; (void)out_size; (void)ws_size;
  const int* x = (const int*)d_in[0];
  const float* Wxh = (const float*)d_in[1];
  const float* Whh = (const float*)d_in[2];
  const float* bh = (const float*)d_in[3];
  const float* Wo = (const float*)d_in[4];
  const float* Bo = (const float*)d_in[5];
  float* out = (float*)d_out;

  // workspace: WhhP7 512KB @0 | WhhS 384KB @524288 | WoT 4MB @917504 |
  //            hs 16MB @5111808
  unsigned int* WhhP7 = (unsigned int*)d_ws;
  unsigned int* WhhS = (unsigned int*)((char*)d_ws + 524288);
  unsigned short* WoT = (unsigned short*)((char*)d_ws + 917504);
  unsigned short* hs = (unsigned short*)((char*)d_ws + 5111808);

  hipLaunchKernelGGL(pack_whh7, dim3(512), dim3(256), 0, stream, Whh, WhhP7);
  hipLaunchKernelGGL(pack_whhS, dim3(384), dim3(256), 0, stream, Whh, WhhS);
  hipLaunchKernelGGL(transpose_wo, dim3(64, 8), dim3(256), 0, stream, Wo, WoT);
  hipLaunchKernelGGL(rnn_scan9, dim3(64), dim3(512), 0, stream, x, Wxh, WhhP7, WhhS, bh, hs);
  hipLaunchKernelGGL(gemm_out, dim3(4096), dim3(256), 0, stream, hs, WoT, Bo, out);
}

// Round 14
// 613.791 us; speedup vs baseline: 1.5674x; 1.5674x over previous
//
#include <hip/hip_runtime.h>

// Problem constants: B=64, T=256, V=4096, H=512
// Inputs: x[B*T] i32, Wxh[V,H] f32, Whh[H,H] f32, bh[H] f32, Wo[H,V] f32, Bo[V] f32
// Output: out[B,T,V] f32 = (scan hs) @ Wo + Bo

typedef __fp16 half2_t __attribute__((ext_vector_type(2)));
typedef __attribute__((ext_vector_type(8))) short short8;   // 8 bf16 (MFMA A/B frag)
typedef __attribute__((ext_vector_type(4))) float f32x4;    // MFMA C/D frag

__device__ __forceinline__ unsigned short f32_to_bf16(float f) {
  unsigned int u = __builtin_bit_cast(unsigned int, f);
  u = (u + 0x7FFFu + ((u >> 16) & 1u)) >> 16;  // RNE
  return (unsigned short)u;
}

__device__ __forceinline__ unsigned int pack_f16x2(float a, float b) {
  half2_t h = __builtin_amdgcn_cvt_pkrtz(a, b);
  return __builtin_bit_cast(unsigned int, h);
}

__device__ __forceinline__ float fdot2_(unsigned int w, unsigned int h, float acc) {
  return __builtin_amdgcn_fdot2(__builtin_bit_cast(half2_t, w),
                                __builtin_bit_cast(half2_t, h), acc, false);
}

__device__ __forceinline__ void glds16(const void* g, void* lds) {
  __builtin_amdgcn_global_load_lds(
      (const __attribute__((address_space(1))) unsigned int*)g,
      (__attribute__((address_space(3))) unsigned int*)lds, 16, 0, 0);
}

// ---------------------------------------------------------------------------
// Prep 1: Whh -> WhhB, per-slice LDS image. u32 flat idx = G*4+e,
// G = ((s*4 + q)*16 + u)*128 + c: f16 pair p = q*64 + u*4 + e (h elems
// 2p,2p+1) of column j = s*128 + c. Block s stages G in [s*8192,(s+1)*8192)
// (uint4) linearly -> coalesced. Block 0 also zeroes the sync flags.
// ---------------------------------------------------------------------------
__global__ __launch_bounds__(256) void pack_whhB(const float* __restrict__ Whh,
                                                 unsigned int* __restrict__ WhhB,
                                                 unsigned int* __restrict__ flags) {
  int idx = blockIdx.x * 256 + threadIdx.x;  // 131072 u32 total
  int e = idx & 3;
  int G = idx >> 2;
  int c = G & 127;
  int u = (G >> 7) & 15;
  int q = (G >> 11) & 3;
  int s = G >> 13;
  int p = q * 64 + u * 4 + e;   // f16-pair index 0..255
  int j = s * 128 + c;          // column
  float f0 = Whh[(2 * p) * 512 + j];
  float f1 = Whh[(2 * p + 1) * 512 + j];
  WhhB[idx] = pack_f16x2(f0, f1);
  if (blockIdx.x == 0) {
    for (int k = threadIdx.x; k < 1024; k += 256) flags[k] = 0u;  // 64 x 16-pad
  }
}

// ---------------------------------------------------------------------------
// Prep 2: Wo [h][v] f32 -> WoT [v][h] bf16
// ---------------------------------------------------------------------------
__global__ __launch_bounds__(256) void transpose_wo(const float* __restrict__ Wo,
                                                    unsigned short* __restrict__ WoT) {
  __shared__ float tile[64][65];
  const int tv = blockIdx.x;   // 0..63  (V/64)
  const int th = blockIdx.y;   // 0..7   (H/64)
  const int tid = threadIdx.x;
  const int c = tid & 63, r4 = tid >> 6;
#pragma unroll
  for (int p = 0; p < 16; ++p) {
    int hl = p * 4 + r4;
    tile[hl][c] = Wo[(size_t)(th * 64 + hl) * 4096 + tv * 64 + c];
  }
  __syncthreads();
#pragma unroll
  for (int p = 0; p < 16; ++p) {
    int vl = p * 4 + r4;
    WoT[(size_t)(tv * 64 + vl) * 512 + th * 64 + c] = f32_to_bf16(tile[c][vl]);
  }
}

// ---------------------------------------------------------------------------
// Recurrence vA: weights 100% LDS-resident, 4 blocks per batch.
// R13 established a per-CU global-load line-rate wall (~64-92 B/cyc): only
// fewer streamed bytes win. Block (b, s=bid&3) owns cols [128s,128s+128):
// its Whh slice = 128 KB f16 = fits LDS -> ZERO per-step global weight reads.
// Per step, sibling blocks exchange h (512 f16) via LLC using RELAXED
// AGENT-scope atomic ops ONLY (sc-bit bypass; no fences -> no L1/L2
// invalidation, the R7 killer; FETCH_SIZE is the tell). Ordering: scoped
// stores -> __syncthreads (vmcnt drain) -> flag fetch_add; readers spin
// flag >= 4t -> barrier -> scoped loads -> LDS. 1 block/CU (LDS 135KB),
// 256 blocks co-resident by capacity -> spin cannot deadlock.
// Thread (c=tid&127, q=tid>>7): col 128s+c, k-quarter q; 64 fdot2 via 4
// independent accumulators; partials reduced in LDS; tid<64 finalize 2 cols.
// ---------------------------------------------------------------------------
#define DOTU(u_, A) do { \
  const uint4 w_ = wlds[(q16 + (u_)) * 128 + c]; \
  const uint4 h_ = hbuf[q16 + (u_)]; \
  A = fdot2_(w_.x, h_.x, A); A = fdot2_(w_.y, h_.y, A); \
  A = fdot2_(w_.z, h_.z, A); A = fdot2_(w_.w, h_.w, A); } while (0)

__global__ __launch_bounds__(512) void rnn_scanA(const int* __restrict__ x,
                                                 const float* __restrict__ Wxh,
                                                 const unsigned int* __restrict__ WhhB,
                                                 const float* __restrict__ bh,
                                                 unsigned short* __restrict__ hs,
                                                 unsigned int* hG,
                                                 unsigned int* flags) {
  __shared__ uint4 wlds[8192];   // 128 KB: this block's full weight slice
  __shared__ uint4 hbuf[64];     // 512 h values as f16 pairs
  __shared__ float pbuf[512];    // partials [q][c]
  __shared__ int toks[256];
  const int bid = blockIdx.x;
  const int s = bid & 3;         // column-slice
  const int b = bid >> 2;        // batch
  const int tid = threadIdx.x;
  const int c = tid & 127;
  const int q = tid >> 7;        // k-quarter (wave-pair-uniform)
  const int q16 = q * 16;
  const uint4* W4 = (const uint4*)WhhB;

  // stage this block's 128 KB weight slice (coalesced, 16 rounds)
#pragma unroll
  for (int it = 0; it < 16; ++it) {
    int L = it * 512 + tid;
    wlds[L] = W4[s * 8192 + L];
  }
  if (tid < 64) hbuf[tid] = make_uint4(0u, 0u, 0u, 0u);  // h0 = 0
  if (tid < 256) toks[tid] = x[b * 256 + tid];
  __syncthreads();

  unsigned int* hb32 = (unsigned int*)hbuf;      // [256] u32 view
  unsigned int* flagb = flags + b * 16;          // 64B-padded per-batch counter
  const float2* Wxh2 = (const float2*)Wxh;
  const float2* bh2 = (const float2*)bh;
  const float2 bhv = (tid < 64) ? bh2[64 * s + tid] : make_float2(0.f, 0.f);

  for (int t = 0; t < 256; ++t) {
    const int tok = toks[t];
    if (t > 0) {
      // wait for all 4 slices of h_t, then pull them from LLC into LDS
      if (tid == 0) {
        const unsigned tgt = 4u * (unsigned)t;
        while (__hip_atomic_load(flagb, __ATOMIC_RELAXED,
                                 __HIP_MEMORY_SCOPE_AGENT) < tgt) {}
      }
      __syncthreads();
      if (tid < 256)
        hb32[tid] = __hip_atomic_load(&hG[(t & 1) * 16384 + b * 256 + tid],
                                      __ATOMIC_RELAXED, __HIP_MEMORY_SCOPE_AGENT);
      __syncthreads();
    }

    float a0 = 0.f, a1 = 0.f, a2 = 0.f, a3 = 0.f;
    DOTU(0, a0);  DOTU(1, a1);  DOTU(2, a2);  DOTU(3, a3);
    DOTU(4, a0);  DOTU(5, a1);  DOTU(6, a2);  DOTU(7, a3);
    DOTU(8, a0);  DOTU(9, a1);  DOTU(10, a2); DOTU(11, a3);
    DOTU(12, a0); DOTU(13, a1); DOTU(14, a2); DOTU(15, a3);
    pbuf[q * 128 + c] = (a0 + a1) + (a2 + a3);
    __syncthreads();

    if (tid < 64) {  // finalize cols j0 = 128s+2*tid, j0+1
      const int f = tid;
      const float s1 = pbuf[2 * f] + pbuf[128 + 2 * f] + pbuf[256 + 2 * f] + pbuf[384 + 2 * f];
      const float s2 = pbuf[2 * f + 1] + pbuf[128 + 2 * f + 1] + pbuf[256 + 2 * f + 1] + pbuf[384 + 2 * f + 1];
      const float2 xv = Wxh2[(size_t)tok * 256 + 64 * s + f];
      const float h1 = tanhf(xv.x + s1 + bhv.x);
      const float h2 = tanhf(xv.y + s2 + bhv.y);
      // h_{t+1} slice -> LLC (scoped store, no fence)
      __hip_atomic_store(&hG[((t + 1) & 1) * 16384 + b * 256 + 64 * s + f],
                         pack_f16x2(h1, h2), __ATOMIC_RELAXED,
                         __HIP_MEMORY_SCOPE_AGENT);
      // bf16 pair -> hs for the output GEMM
      unsigned int bb = (unsigned int)f32_to_bf16(h1) |
                        ((unsigned int)f32_to_bf16(h2) << 16);
      ((unsigned int*)hs)[(size_t)(b * 256 + t) * 256 + 64 * s + f] = bb;
    }
    __syncthreads();  // drains vmcnt: scoped stores complete before flag post
    if (tid == 0)
      __hip_atomic_fetch_add(flagb, 1u, __ATOMIC_RELAXED, __HIP_MEMORY_SCOPE_AGENT);
  }
}

// ---------------------------------------------------------------------------
// Output GEMM: C[16384,4096] = A[16384,512](bf16) @ WoT^T + Bo.  m97 structure.
// ---------------------------------------------------------------------------
__global__ __launch_bounds__(256) void gemm_out(const unsigned short* __restrict__ A,
                                                const unsigned short* __restrict__ Bt,
                                                const float* __restrict__ Bo,
                                                float* __restrict__ C) {
  __shared__ alignas(16) unsigned short As[128 * 32];
  __shared__ alignas(16) unsigned short Bs[128 * 32];
  const int tid = threadIdx.x;
  const int lane = tid & 63, wid = tid >> 6;
  const int bn = blockIdx.x & 31, bm = blockIdx.x >> 5;
  const int wr = wid >> 1, wc = wid & 1;

  f32x4 acc[4][4] = {};

  const unsigned short* Ag = A + (size_t)(bm * 128 + (tid >> 2)) * 512 + (tid & 3) * 8;
  const unsigned short* Bg = Bt + (size_t)(bn * 128 + (tid >> 2)) * 512 + (tid & 3) * 8;
  char* AsW = (char*)As + wid * 1024;
  char* BsW = (char*)Bs + wid * 1024;

  const int laneRow = lane & 15;
  const int k0 = (lane >> 4) * 8;

  for (int kt = 0; kt < 16; ++kt) {
    __syncthreads();
    const unsigned short* a0 = Ag + kt * 32;
    const unsigned short* b0 = Bg + kt * 32;
    glds16(a0,            AsW);
    glds16(a0 + 64 * 512, AsW + 4096);
    glds16(b0,            BsW);
    glds16(b0 + 64 * 512, BsW + 4096);
    __syncthreads();

    short8 af[4], bf[4];
#pragma unroll
    for (int f = 0; f < 4; ++f)
      af[f] = *(const short8*)&As[(wr * 64 + f * 16 + laneRow) * 32 + k0];
#pragma unroll
    for (int f = 0; f < 4; ++f)
      bf[f] = *(const short8*)&Bs[(wc * 64 + f * 16 + laneRow) * 32 + k0];
#pragma unroll
    for (int fm = 0; fm < 4; ++fm)
#pragma unroll
      for (int fn = 0; fn < 4; ++fn)
        acc[fm][fn] = __builtin_amdgcn_mfma_f32_16x16x32_bf16(af[fm], bf[fn], acc[fm][fn], 0, 0, 0);
  }

  const int mg0 = bm * 128 + wr * 64, ng0 = bn * 128 + wc * 64;
#pragma unroll
  for (int fn = 0; fn < 4; ++fn) {
    const int col = ng0 + fn * 16 + laneRow;
    const float bo = Bo[col];
#pragma unroll
    for (int fm = 0; fm < 4; ++fm) {
      const int row0 = mg0 + fm * 16 + (lane >> 4) * 4;
#pragma unroll
      for (int r = 0; r < 4; ++r)
        C[(size_t)(row0 + r) * 4096 + col] = acc[fm][fn][r] + bo;
    }
  }
}

// ---------------------------------------------------------------------------
extern "C" void kernel_launch(void* const* d_in, const int* in_sizes, int n_in,
                              void* d_out, int out_size, void* d_ws, size_t ws_size,
                              hipStream_t stream) {
  (void)in_sizes; (void)n_in; (void)out_size; (void)ws_size;
  const int* x = (const int*)d_in[0];
  const float* Wxh = (const float*)d_in[1];
  const float* Whh = (const float*)d_in[2];
  const float* bh = (const float*)d_in[3];
  const float* Wo = (const float*)d_in[4];
  const float* Bo = (const float*)d_in[5];
  float* out = (float*)d_out;

  // workspace map (bytes):
  //   WhhB   @ 0         512 KB
  //   WoT    @ 524288    4 MB
  //   hs     @ 4718592   16 MB
  //   hG     @ 21495808  128 KB   (2 x 64 x 256 u32 = f16 pairs)
  //   flags  @ 21626880  4 KB
  unsigned int* WhhB = (unsigned int*)d_ws;
  unsigned short* WoT = (unsigned short*)((char*)d_ws + 524288);
  unsigned short* hs = (unsigned short*)((char*)d_ws + 4718592);
  unsigned int* hG = (unsigned int*)((char*)d_ws + 21495808);
  unsigned int* flags = (unsigned int*)((char*)d_ws + 21626880);

  hipLaunchKernelGGL(pack_whhB, dim3(512), dim3(256), 0, stream, Whh, WhhB, flags);
  hipLaunchKernelGGL(transpose_wo, dim3(64, 8), dim3(256), 0, stream, Wo, WoT);
  hipLaunchKernelGGL(rnn_scanA, dim3(256), dim3(512), 0, stream, x, Wxh, WhhB, bh,
                     hs, hG, flags);
  hipLaunchKernelGGL(gemm_out, dim3(4096), dim3(256), 0, stream, hs, WoT, Bo, out);
}

// Round 15
// 544.413 us; speedup vs baseline: 1.7671x; 1.1274x over previous
//
#include <hip/hip_runtime.h>

// Problem constants: B=64, T=256, V=4096, H=512
// Inputs: x[B*T] i32, Wxh[V,H] f32, Whh[H,H] f32, bh[H] f32, Wo[H,V] f32, Bo[V] f32
// Output: out[B,T,V] f32 = (scan hs) @ Wo + Bo

typedef __fp16 half2_t __attribute__((ext_vector_type(2)));
typedef __attribute__((ext_vector_type(8))) short short8;   // 8 bf16 (MFMA A/B frag)
typedef __attribute__((ext_vector_type(4))) float f32x4;    // MFMA C/D frag

__device__ __forceinline__ unsigned short f32_to_bf16(float f) {
  unsigned int u = __builtin_bit_cast(unsigned int, f);
  u = (u + 0x7FFFu + ((u >> 16) & 1u)) >> 16;  // RNE
  return (unsigned short)u;
}

__device__ __forceinline__ unsigned int pack_f16x2(float a, float b) {
  half2_t h = __builtin_amdgcn_cvt_pkrtz(a, b);
  return __builtin_bit_cast(unsigned int, h);
}

__device__ __forceinline__ float fdot2_(unsigned int w, unsigned int h, float acc) {
  return __builtin_amdgcn_fdot2(__builtin_bit_cast(half2_t, w),
                                __builtin_bit_cast(half2_t, h), acc, false);
}

__device__ __forceinline__ void glds16(const void* g, void* lds) {
  __builtin_amdgcn_global_load_lds(
      (const __attribute__((address_space(1))) unsigned int*)g,
      (__attribute__((address_space(3))) unsigned int*)lds, 16, 0, 0);
}

// ---------------------------------------------------------------------------
// Prep 1: Whh -> WhhB per-slice LDS image (same as R14). u32 flat idx = G*4+e,
// G = ((s*4 + q)*16 + u)*128 + c: f16 pair p = q*64 + u*4 + e of column
// j = s*128 + c. Also zeroes the tagged h-exchange buffer hG64 every launch
// (graph replays rerun this kernel, so stale tags can never alias).
// ---------------------------------------------------------------------------
__global__ __launch_bounds__(256) void pack_whhB(const float* __restrict__ Whh,
                                                 unsigned int* __restrict__ WhhB,
                                                 unsigned long long* __restrict__ hG64) {
  int idx = blockIdx.x * 256 + threadIdx.x;  // 131072 threads
  int e = idx & 3;
  int G = idx >> 2;
  int c = G & 127;
  int u = (G >> 7) & 15;
  int q = (G >> 11) & 3;
  int s = G >> 13;
  int p = q * 64 + u * 4 + e;   // f16-pair index 0..255
  int j = s * 128 + c;          // column
  float f0 = Whh[(2 * p) * 512 + j];
  float f1 = Whh[(2 * p + 1) * 512 + j];
  WhhB[idx] = pack_f16x2(f0, f1);
  if (idx < 32768) hG64[idx] = 0ull;  // tag 0 != any target t>=1
}

// ---------------------------------------------------------------------------
// Prep 2: Wo [h][v] f32 -> WoT [v][h] bf16
// ---------------------------------------------------------------------------
__global__ __launch_bounds__(256) void transpose_wo(const float* __restrict__ Wo,
                                                    unsigned short* __restrict__ WoT) {
  __shared__ float tile[64][65];
  const int tv = blockIdx.x;   // 0..63  (V/64)
  const int th = blockIdx.y;   // 0..7   (H/64)
  const int tid = threadIdx.x;
  const int c = tid & 63, r4 = tid >> 6;
#pragma unroll
  for (int p = 0; p < 16; ++p) {
    int hl = p * 4 + r4;
    tile[hl][c] = Wo[(size_t)(th * 64 + hl) * 4096 + tv * 64 + c];
  }
  __syncthreads();
#pragma unroll
  for (int p = 0; p < 16; ++p) {
    int vl = p * 4 + r4;
    WoT[(size_t)(tv * 64 + vl) * 512 + th * 64 + c] = f32_to_bf16(tile[c][vl]);
  }
}

// ---------------------------------------------------------------------------
// Recurrence vB: R14 structure (weights 100% LDS, 4 blocks/batch) with the
// exchange collapsed to ONE LLC round trip. R14's 3.6k-cyc/step exchange was
// 4 serial LLC latencies (store-drain, flag add, tid0-poll, data pull). Fix:
// TAGGED PAYLOADS -- each h-pair is stored as an atomic u64
// (tag=t+1 | 2xf16); 8B stores are HW-atomic so data+tag arrive together.
// 192 reader threads spin on their OWN word (tag==t), drop payload into LDS,
// one barrier, dots. No flags, no drain ordering, no rebroadcast.
// WAR safety: reader seeing tag t implies that sibling finished step t-1
// INCLUDING its reads of the slot this block overwrites at step t (same
// invariant as R14's counter). Stale replay tags: pack_whhB zeroes hG64.
// ---------------------------------------------------------------------------
#define DOTU(u_, A) do { \
  const uint4 w_ = wlds[(q16 + (u_)) * 128 + c]; \
  const uint4 h_ = hbuf[q16 + (u_)]; \
  A = fdot2_(w_.x, h_.x, A); A = fdot2_(w_.y, h_.y, A); \
  A = fdot2_(w_.z, h_.z, A); A = fdot2_(w_.w, h_.w, A); } while (0)

__global__ __launch_bounds__(512) void rnn_scanB(const int* __restrict__ x,
                                                 const float* __restrict__ Wxh,
                                                 const unsigned int* __restrict__ WhhB,
                                                 const float* __restrict__ bh,
                                                 unsigned short* __restrict__ hs,
                                                 unsigned long long* hG64) {
  __shared__ uint4 wlds[8192];   // 128 KB: this block's full weight slice
  __shared__ uint4 hbuf[64];     // 512 h values as f16 pairs (single buffer)
  __shared__ float pbuf[512];    // partials [q][c]
  __shared__ int toks[256];
  const int bid = blockIdx.x;
  const int s = bid & 3;         // column-slice
  const int b = bid >> 2;        // batch
  const int tid = threadIdx.x;
  const int c = tid & 127;
  const int q = tid >> 7;        // k-quarter
  const int q16 = q * 16;
  const uint4* W4 = (const uint4*)WhhB;

  // stage this block's 128 KB weight slice (coalesced, 16 rounds)
#pragma unroll
  for (int it = 0; it < 16; ++it) {
    int L = it * 512 + tid;
    wlds[L] = W4[s * 8192 + L];
  }
  if (tid < 64) hbuf[tid] = make_uint4(0u, 0u, 0u, 0u);  // h0 = 0
  if (tid < 256) toks[tid] = x[b * 256 + tid];
  __syncthreads();

  unsigned int* hb32 = (unsigned int*)hbuf;      // [256] u32 view of h pairs
  const float2* Wxh2 = (const float2*)Wxh;
  const float2* bh2 = (const float2*)bh;
  const float2 bhv = (tid < 64) ? bh2[64 * s + tid] : make_float2(0.f, 0.f);

  for (int t = 0; t < 256; ++t) {
    const int tok = toks[t];
    if (t > 0) {
      // pull the 192 remote h-pairs: spin on own tagged word, one round trip
      if (tid < 192) {
        const int r = (tid < s * 64) ? tid : tid + 64;  // skip own slice
        const unsigned long long* src =
            hG64 + (((size_t)(t & 1)) << 14) + b * 256 + r;
        unsigned long long v;
        do {
          v = __hip_atomic_load(src, __ATOMIC_RELAXED, __HIP_MEMORY_SCOPE_AGENT);
        } while ((unsigned)(v >> 32) != (unsigned)t);
        hb32[r] = (unsigned)v;
      }
      __syncthreads();
    }

    float a0 = 0.f, a1 = 0.f, a2 = 0.f, a3 = 0.f;
    DOTU(0, a0);  DOTU(1, a1);  DOTU(2, a2);  DOTU(3, a3);
    DOTU(4, a0);  DOTU(5, a1);  DOTU(6, a2);  DOTU(7, a3);
    DOTU(8, a0);  DOTU(9, a1);  DOTU(10, a2); DOTU(11, a3);
    DOTU(12, a0); DOTU(13, a1); DOTU(14, a2); DOTU(15, a3);
    pbuf[q * 128 + c] = (a0 + a1) + (a2 + a3);
    __syncthreads();

    if (tid < 64) {  // finalize cols j0 = 128s+2*tid, j0+1
      const int f = tid;
      const float s1 = pbuf[2 * f] + pbuf[128 + 2 * f] + pbuf[256 + 2 * f] + pbuf[384 + 2 * f];
      const float s2 = pbuf[2 * f + 1] + pbuf[128 + 2 * f + 1] + pbuf[256 + 2 * f + 1] + pbuf[384 + 2 * f + 1];
      const float2 xv = Wxh2[(size_t)tok * 256 + 64 * s + f];
      const float h1 = tanhf(xv.x + s1 + bhv.x);
      const float h2 = tanhf(xv.y + s2 + bhv.y);
      const unsigned int hp = pack_f16x2(h1, h2);
      // tagged payload -> LLC: data and tag land atomically (8B store)
      __hip_atomic_store(hG64 + (((size_t)((t + 1) & 1)) << 14) + b * 256 + 64 * s + f,
                         ((unsigned long long)(unsigned)(t + 1) << 32) | hp,
                         __ATOMIC_RELAXED, __HIP_MEMORY_SCOPE_AGENT);
      hb32[64 * s + f] = hp;  // own slice for next step's dots (local, no pull)
      // bf16 pair -> hs for the output GEMM
      unsigned int bb = (unsigned int)f32_to_bf16(h1) |
                        ((unsigned int)f32_to_bf16(h2) << 16);
      ((unsigned int*)hs)[(size_t)(b * 256 + t) * 256 + 64 * s + f] = bb;
    }
    __syncthreads();  // own-slice LDS update visible; pbuf reusable
  }
}

// ---------------------------------------------------------------------------
// Output GEMM: C[16384,4096] = A[16384,512](bf16) @ WoT^T + Bo.  m97 structure.
// ---------------------------------------------------------------------------
__global__ __launch_bounds__(256) void gemm_out(const unsigned short* __restrict__ A,
                                                const unsigned short* __restrict__ Bt,
                                                const float* __restrict__ Bo,
                                                float* __restrict__ C) {
  __shared__ alignas(16) unsigned short As[128 * 32];
  __shared__ alignas(16) unsigned short Bs[128 * 32];
  const int tid = threadIdx.x;
  const int lane = tid & 63, wid = tid >> 6;
  const int bn = blockIdx.x & 31, bm = blockIdx.x >> 5;
  const int wr = wid >> 1, wc = wid & 1;

  f32x4 acc[4][4] = {};

  const unsigned short* Ag = A + (size_t)(bm * 128 + (tid >> 2)) * 512 + (tid & 3) * 8;
  const unsigned short* Bg = Bt + (size_t)(bn * 128 + (tid >> 2)) * 512 + (tid & 3) * 8;
  char* AsW = (char*)As + wid * 1024;
  char* BsW = (char*)Bs + wid * 1024;

  const int laneRow = lane & 15;
  const int k0 = (lane >> 4) * 8;

  for (int kt = 0; kt < 16; ++kt) {
    __syncthreads();
    const unsigned short* a0 = Ag + kt * 32;
    const unsigned short* b0 = Bg + kt * 32;
    glds16(a0,            AsW);
    glds16(a0 + 64 * 512, AsW + 4096);
    glds16(b0,            BsW);
    glds16(b0 + 64 * 512, BsW + 4096);
    __syncthreads();

    short8 af[4], bf[4];
#pragma unroll
    for (int f = 0; f < 4; ++f)
      af[f] = *(const short8*)&As[(wr * 64 + f * 16 + laneRow) * 32 + k0];
#pragma unroll
    for (int f = 0; f < 4; ++f)
      bf[f] = *(const short8*)&Bs[(wc * 64 + f * 16 + laneRow) * 32 + k0];
#pragma unroll
    for (int fm = 0; fm < 4; ++fm)
#pragma unroll
      for (int fn = 0; fn < 4; ++fn)
        acc[fm][fn] = __builtin_amdgcn_mfma_f32_16x16x32_bf16(af[fm], bf[fn], acc[fm][fn], 0, 0, 0);
  }

  const int mg0 = bm * 128 + wr * 64, ng0 = bn * 128 + wc * 64;
#pragma unroll
  for (int fn = 0; fn < 4; ++fn) {
    const int col = ng0 + fn * 16 + laneRow;
    const float bo = Bo[col];
#pragma unroll
    for (int fm = 0; fm < 4; ++fm) {
      const int row0 = mg0 + fm * 16 + (lane >> 4) * 4;
#pragma unroll
      for (int r = 0; r < 4; ++r)
        C[(size_t)(row0 + r) * 4096 + col] = acc[fm][fn][r] + bo;
    }
  }
}

// ---------------------------------------------------------------------------
extern "C" void kernel_launch(void* const* d_in, const int* in_sizes, int n_in,
                              void* d_out, int out_size, void* d_ws, size_t ws_size,
                              hipStream_t stream) {
  (void)in_sizes; (void)n_in; (void)out_size; (void)ws_size;
  const int* x = (const int*)d_in[0];
  const float* Wxh = (const float*)d_in[1];
  const float* Whh = (const float*)d_in[2];
  const float* bh = (const float*)d_in[3];
  const float* Wo = (const float*)d_in[4];
  const float* Bo = (const float*)d_in[5];
  float* out = (float*)d_out;

  // workspace map (bytes):
  //   WhhB   @ 0         512 KB
  //   WoT    @ 524288    4 MB
  //   hs     @ 4718592   16 MB
  //   hG64   @ 21495808  256 KB   (2 x 64 x 256 tagged u64)
  unsigned int* WhhB = (unsigned int*)d_ws;
  unsigned short* WoT = (unsigned short*)((char*)d_ws + 524288);
  unsigned short* hs = (unsigned short*)((char*)d_ws + 4718592);
  unsigned long long* hG64 = (unsigned long long*)((char*)d_ws + 21495808);

  hipLaunchKernelGGL(pack_whhB, dim3(512), dim3(256), 0, stream, Whh, WhhB, hG64);
  hipLaunchKernelGGL(transpose_wo, dim3(64, 8), dim3(256), 0, stream, Wo, WoT);
  hipLaunchKernelGGL(rnn_scanB, dim3(256), dim3(512), 0, stream, x, Wxh, WhhB, bh,
                     hs, hG64);
  hipLaunchKernelGGL(gemm_out, dim3(4096), dim3(256), 0, stream, hs, WoT, Bo, out);
}

// Round 17
// 517.794 us; speedup vs baseline: 1.8579x; 1.0514x over previous
//
#include <hip/hip_runtime.h>

// Problem constants: B=64, T=256, V=4096, H=512
// Inputs: x[B*T] i32, Wxh[V,H] f32, Whh[H,H] f32, bh[H] f32, Wo[H,V] f32, Bo[V] f32
// Output: out[B,T,V] f32 = (scan hs) @ Wo + Bo

typedef __fp16 half2_t __attribute__((ext_vector_type(2)));
typedef __attribute__((ext_vector_type(8))) short short8;   // 8 bf16 (MFMA A/B frag)
typedef __attribute__((ext_vector_type(4))) float f32x4;    // MFMA C/D frag

__device__ __forceinline__ unsigned short f32_to_bf16(float f) {
  unsigned int u = __builtin_bit_cast(unsigned int, f);
  u = (u + 0x7FFFu + ((u >> 16) & 1u)) >> 16;  // RNE
  return (unsigned short)u;
}

__device__ __forceinline__ unsigned int pack_f16x2(float a, float b) {
  half2_t h = __builtin_amdgcn_cvt_pkrtz(a, b);
  return __builtin_bit_cast(unsigned int, h);
}

__device__ __forceinline__ float fdot2_(unsigned int w, unsigned int h, float acc) {
  return __builtin_amdgcn_fdot2(__builtin_bit_cast(half2_t, w),
                                __builtin_bit_cast(half2_t, h), acc, false);
}

__device__ __forceinline__ void glds16(const void* g, void* lds) {
  __builtin_amdgcn_global_load_lds(
      (const __attribute__((address_space(1))) unsigned int*)g,
      (__attribute__((address_space(3))) unsigned int*)lds, 16, 0, 0);
}

// ---------------------------------------------------------------------------
// Prep 1: Whh -> WhhB per-slice LDS image (R14/R15 layout). u32 flat idx =
// G*4+e, G = ((s*4 + q)*16 + u)*128 + c: f16 pair p = q*64 + u*4 + e of
// column j = s*128 + c.  (In-scan chunk index kc = q*16+u, i.e. wlds[kc*128+c]
// holds pairs [4kc,4kc+4) of column s*128+c.)  Zeroes hG64 tags every launch
// (graph replays rerun this kernel -> stale tags can never alias).
// ---------------------------------------------------------------------------
__global__ __launch_bounds__(256) void pack_whhB(const float* __restrict__ Whh,
                                                 unsigned int* __restrict__ WhhB,
                                                 unsigned long long* __restrict__ hG64) {
  int idx = blockIdx.x * 256 + threadIdx.x;  // 131072 threads
  int e = idx & 3;
  int G = idx >> 2;
  int c = G & 127;
  int u = (G >> 7) & 15;
  int q = (G >> 11) & 3;
  int s = G >> 13;
  int p = q * 64 + u * 4 + e;   // f16-pair index 0..255
  int j = s * 128 + c;          // column
  float f0 = Whh[(2 * p) * 512 + j];
  float f1 = Whh[(2 * p + 1) * 512 + j];
  WhhB[idx] = pack_f16x2(f0, f1);
  if (idx < 32768) hG64[idx] = 0ull;  // tag 0 != any target t>=1
}

// ---------------------------------------------------------------------------
// Prep 2: Wo [h][v] f32 -> WoT [v][h] bf16
// ---------------------------------------------------------------------------
__global__ __launch_bounds__(256) void transpose_wo(const float* __restrict__ Wo,
                                                    unsigned short* __restrict__ WoT) {
  __shared__ float tile[64][65];
  const int tv = blockIdx.x;   // 0..63  (V/64)
  const int th = blockIdx.y;   // 0..7   (H/64)
  const int tid = threadIdx.x;
  const int c = tid & 63, r4 = tid >> 6;
#pragma unroll
  for (int p = 0; p < 16; ++p) {
    int hl = p * 4 + r4;
    tile[hl][c] = Wo[(size_t)(th * 64 + hl) * 4096 + tv * 64 + c];
  }
  __syncthreads();
#pragma unroll
  for (int p = 0; p < 16; ++p) {
    int vl = p * 4 + r4;
    WoT[(size_t)(tv * 64 + vl) * 512 + th * 64 + c] = f32_to_bf16(tile[c][vl]);
  }
}

// ---------------------------------------------------------------------------
// Recurrence vD: R15 protocol (UNCHANGED sync semantics -- R16's L2 fast path
// deadlocked: sc0 spin-load likely re-caches in L1 and never sees the plain
// store; reverted). Three critical-chain trims instead:
//  (1) xv prefetch at loop top (R15 paid ~200cyc L2 hit inside finalize)
//  (2) interleaved k-walk: thread (c,q) walks kc = 16Q + 4i + q, so its 4
//      own-quarter chunks (Q=s, h known locally from last step) are computed
//      BEFORE polling -> ~275 cyc of dots overlap the store->visibility
//      window. Same wlds layout, only walk order changes.
//  (3) finalize: 128 thr x 1 col (4 pbuf reads), pack u-pairs via shfl, store
//      tagged PRE-TANH u first (chain ends at store); readers tanh on
//      receipt; writer re-derives own h from the same rounded f16 u.
// ---------------------------------------------------------------------------
#define DOTK(kc_, A) do { \
  const uint4 w_ = wlds[(kc_) * 128 + c]; \
  const uint4 h_ = hbuf[(kc_)]; \
  A = fdot2_(w_.x, h_.x, A); A = fdot2_(w_.y, h_.y, A); \
  A = fdot2_(w_.z, h_.z, A); A = fdot2_(w_.w, h_.w, A); } while (0)

__global__ __launch_bounds__(512) void rnn_scanD(const int* __restrict__ x,
                                                 const float* __restrict__ Wxh,
                                                 const unsigned int* __restrict__ WhhB,
                                                 const float* __restrict__ bh,
                                                 unsigned short* __restrict__ hs,
                                                 unsigned long long* hG64) {
  __shared__ uint4 wlds[8192];   // 128 KB: this block's full weight slice
  __shared__ uint4 hbuf[64];     // 512 h values as f16 pairs
  __shared__ float pbuf[512];    // partials [q][c]
  __shared__ int toks[256];
  const int bid = blockIdx.x;
  const int s = bid & 3;         // column-slice (R15 mapping, proven)
  const int b = bid >> 2;        // batch
  const int tid = threadIdx.x;
  const int c = tid & 127;
  const int q = tid >> 7;        // k-phase within each quarter
  const int s16 = s * 16;
  const uint4* W4 = (const uint4*)WhhB;

  // stage this block's 128 KB weight slice (coalesced, 16 rounds)
#pragma unroll
  for (int it = 0; it < 16; ++it) {
    int L = it * 512 + tid;
    wlds[L] = W4[s * 8192 + L];
  }
  if (tid < 64) hbuf[tid] = make_uint4(0u, 0u, 0u, 0u);  // h0 = 0
  if (tid < 256) toks[tid] = x[b * 256 + tid];
  __syncthreads();

  unsigned int* hb32 = (unsigned int*)hbuf;      // [256] u32 view of h pairs
  const float bhj = (tid < 128) ? bh[s * 128 + tid] : 0.f;

  for (int t = 0; t < 256; ++t) {
    const int tok = toks[t];
    // (1) prefetch xv now; resolved long before finalize uses it
    const float xv = (tid < 128) ? Wxh[(size_t)tok * 512 + s * 128 + tid] : 0.f;

    float a0 = 0.f, a1 = 0.f, a2 = 0.f, a3 = 0.f;
    // (2) phase 1: own-quarter chunks (h from local write last step) --
    // overlaps the siblings' store->LLC-visibility window
    DOTK(s16 + 0 + q, a0); DOTK(s16 + 4 + q, a1);
    DOTK(s16 + 8 + q, a2); DOTK(s16 + 12 + q, a3);

    if (t > 0 && tid < 192) {
      // pull 192 remote u-pairs: spin on own tagged word, tanh on receipt
      const int r = (tid < s * 64) ? tid : tid + 64;  // skip own slice
      const unsigned long long* src =
          hG64 + (((size_t)(t & 1)) << 14) + b * 256 + r;
      unsigned long long v;
      do {
        v = __hip_atomic_load(src, __ATOMIC_RELAXED, __HIP_MEMORY_SCOPE_AGENT);
      } while ((unsigned)(v >> 32) != (unsigned)t);
      half2_t up = __builtin_bit_cast(half2_t, (unsigned)v);
      hb32[r] = pack_f16x2(tanhf((float)up.x), tanhf((float)up.y));
    }
    __syncthreads();

    // phase 2: the three remote quarters
    {
      int m1 = ((s + 1) & 3) * 16;
      DOTK(m1 + 0 + q, a0); DOTK(m1 + 4 + q, a1);
      DOTK(m1 + 8 + q, a2); DOTK(m1 + 12 + q, a3);
      int m2 = ((s + 2) & 3) * 16;
      DOTK(m2 + 0 + q, a0); DOTK(m2 + 4 + q, a1);
      DOTK(m2 + 8 + q, a2); DOTK(m2 + 12 + q, a3);
      int m3 = ((s + 3) & 3) * 16;
      DOTK(m3 + 0 + q, a0); DOTK(m3 + 4 + q, a1);
      DOTK(m3 + 8 + q, a2); DOTK(m3 + 12 + q, a3);
    }
    pbuf[q * 128 + c] = (a0 + a1) + (a2 + a3);
    __syncthreads();

    // (3) finalize: 128 threads x 1 col; store tagged pre-tanh u FIRST
    if (tid < 128) {
      const float ssum = pbuf[tid] + pbuf[tid + 128] + pbuf[tid + 256] + pbuf[tid + 384];
      const float u1 = xv + ssum + bhj;
      const float u2 = __shfl_down(u1, 1);  // odd partner's u (pair in-wave)
      if (!(tid & 1)) {
        const unsigned int up = pack_f16x2(u1, u2);
        __hip_atomic_store(
            hG64 + (((size_t)((t + 1) & 1)) << 14) + b * 256 + 64 * s + (tid >> 1),
            ((unsigned long long)(unsigned)(t + 1) << 32) | up,
            __ATOMIC_RELAXED, __HIP_MEMORY_SCOPE_AGENT);
        // own h from the SAME rounded u (bit-consistent with readers)
        half2_t uo = __builtin_bit_cast(half2_t, up);
        const float h1 = tanhf((float)uo.x);
        const float h2 = tanhf((float)uo.y);
        hb32[64 * s + (tid >> 1)] = pack_f16x2(h1, h2);
        ((unsigned int*)hs)[(size_t)(b * 256 + t) * 256 + 64 * s + (tid >> 1)] =
            (unsigned int)f32_to_bf16(h1) | ((unsigned int)f32_to_bf16(h2) << 16);
      }
    }
    __syncthreads();  // own-slice LDS update visible; pbuf reusable
  }
}

// ---------------------------------------------------------------------------
// Output GEMM: C[16384,4096] = A[16384,512](bf16) @ WoT^T + Bo.  m97 structure.
// ---------------------------------------------------------------------------
__global__ __launch_bounds__(256) void gemm_out(const unsigned short* __restrict__ A,
                                                const unsigned short* __restrict__ Bt,
                                                const float* __restrict__ Bo,
                                                float* __restrict__ C) {
  __shared__ alignas(16) unsigned short As[128 * 32];
  __shared__ alignas(16) unsigned short Bs[128 * 32];
  const int tid = threadIdx.x;
  const int lane = tid & 63, wid = tid >> 6;
  const int bn = blockIdx.x & 31, bm = blockIdx.x >> 5;
  const int wr = wid >> 1, wc = wid & 1;

  f32x4 acc[4][4] = {};

  const unsigned short* Ag = A + (size_t)(bm * 128 + (tid >> 2)) * 512 + (tid & 3) * 8;
  const unsigned short* Bg = Bt + (size_t)(bn * 128 + (tid >> 2)) * 512 + (tid & 3) * 8;
  char* AsW = (char*)As + wid * 1024;
  char* BsW = (char*)Bs + wid * 1024;

  const int laneRow = lane & 15;
  const int k0 = (lane >> 4) * 8;

  for (int kt = 0; kt < 16; ++kt) {
    __syncthreads();
    const unsigned short* a0 = Ag + kt * 32;
    const unsigned short* b0 = Bg + kt * 32;
    glds16(a0,            AsW);
    glds16(a0 + 64 * 512, AsW + 4096);
    glds16(b0,            BsW);
    glds16(b0 + 64 * 512, BsW + 4096);
    __syncthreads();

    short8 af[4], bf[4];
#pragma unroll
    for (int f = 0; f < 4; ++f)
      af[f] = *(const short8*)&As[(wr * 64 + f * 16 + laneRow) * 32 + k0];
#pragma unroll
    for (int f = 0; f < 4; ++f)
      bf[f] = *(const short8*)&Bs[(wc * 64 + f * 16 + laneRow) * 32 + k0];
#pragma unroll
    for (int fm = 0; fm < 4; ++fm)
#pragma unroll
      for (int fn = 0; fn < 4; ++fn)
        acc[fm][fn] = __builtin_amdgcn_mfma_f32_16x16x32_bf16(af[fm], bf[fn], acc[fm][fn], 0, 0, 0);
  }

  const int mg0 = bm * 128 + wr * 64, ng0 = bn * 128 + wc * 64;
#pragma unroll
  for (int fn = 0; fn < 4; ++fn) {
    const int col = ng0 + fn * 16 + laneRow;
    const float bo = Bo[col];
#pragma unroll
    for (int fm = 0; fm < 4; ++fm) {
      const int row0 = mg0 + fm * 16 + (lane >> 4) * 4;
#pragma unroll
      for (int r = 0; r < 4; ++r)
        C[(size_t)(row0 + r) * 4096 + col] = acc[fm][fn][r] + bo;
    }
  }
}

// ---------------------------------------------------------------------------
extern "C" void kernel_launch(void* const* d_in, const int* in_sizes, int n_in,
                              void* d_out, int out_size, void* d_ws, size_t ws_size,
                              hipStream_t stream) {
  (void)in_sizes; (void)n_in; (void)out_size; (void)ws_size;
  const int* x = (const int*)d_in[0];
  const float* Wxh = (const float*)d_in[1];
  const float* Whh = (const float*)d_in[2];
  const float* bh = (const float*)d_in[3];
  const float* Wo = (const float*)d_in[4];
  const float* Bo = (const float*)d_in[5];
  float* out = (float*)d_out;

  // workspace map (bytes):
  //   WhhB   @ 0         512 KB
  //   WoT    @ 524288    4 MB
  //   hs     @ 4718592   16 MB
  //   hG64   @ 21495808  256 KB   (2 x 64 x 256 tagged u64)
  unsigned int* WhhB = (unsigned int*)d_ws;
  unsigned short* WoT = (unsigned short*)((char*)d_ws + 524288);
  unsigned short* hs = (unsigned short*)((char*)d_ws + 4718592);
  unsigned long long* hG64 = (unsigned long long*)((char*)d_ws + 21495808);

  hipLaunchKernelGGL(pack_whhB, dim3(512), dim3(256), 0, stream, Whh, WhhB, hG64);
  hipLaunchKernelGGL(transpose_wo, dim3(64, 8), dim3(256), 0, stream, Wo, WoT);
  hipLaunchKernelGGL(rnn_scanD, dim3(256), dim3(512), 0, stream, x, Wxh, WhhB, bh,
                     hs, hG64);
  hipLaunchKernelGGL(gemm_out, dim3(4096), dim3(256), 0, stream, hs, WoT, Bo, out);
}